// Round 15
// baseline (120.383 us; speedup 1.0000x reference)
//
#include <hip/hip_runtime.h>
#include <hip/hip_fp16.h>

// DeformConv2d: B=16, Cin=64, Cout=64, H=W=64, K=3, stride=1, pad=1, dil=1
// Round 15: phase A de-LDS'd. NHWC xh makes the regular-conv B-fragment a
// single masked half8 global load (cin contiguous), so phase A needs NO
// colsT staging and NO per-tap barriers. DS ops/thread ~108 -> ~81,
// barriers ~12 -> ~7. Phase B / geometry / prep unchanged from R14 (passing).

#define KOFF 18
#define CTS  136           // colsT stride in halfs (2*64 cin + 8 pad)
#define GSTR 33            // LDS geometry record stride (uint4)

#define W2T_HALFS    (18 * 64 * 32)     // [i][64co][32kl], k' = tap*64+cin
#define WOFF2T_HALFS (18 * 32 * 32)     // [i][32co][32kl]
#define W2T_BYTES    (W2T_HALFS * 2)    // 73728
#define WOFF2T_OFF   W2T_BYTES
#define X_OFF        (W2T_BYTES + WOFF2T_HALFS * 2)   // 110592 (16B aligned)
#define XH_BYTES     (16 * 64 * 64 * 64 * 2)          // 8388608
#define WS_NEED      (X_OFF + XH_BYTES)               // 8499200

typedef _Float16 half8 __attribute__((ext_vector_type(8)));
typedef float floatx4 __attribute__((ext_vector_type(4)));

union H8 { half8 v; __half2 h2[4]; uint4 u; };

// ---------------------------------------------------------------------------
// prep: blocks [0,1024): LDS-tiled transpose of one (b,y) plane (coalesced
// both sides). blocks [1024,1240): weight repack (tap-major f16).
__global__ void prep(const float* __restrict__ x,
                     const float* __restrict__ w_dcn,
                     const float* __restrict__ w_off,
                     _Float16* __restrict__ w2t,
                     _Float16* __restrict__ woff2t,
                     _Float16* __restrict__ xh) {
    const int bi = blockIdx.x;
    const int t  = threadIdx.x;
    if (bi < 1024) {
        const int b = bi >> 6, y = bi & 63;
        __shared__ __align__(16) _Float16 tile[64 * 72];
        const int xx = t & 63;
        const int c4 = t >> 6;
        const float* xp = x + (((size_t)b * 64) * 64 + y) * 64;
#pragma unroll
        for (int p = 0; p < 16; ++p) {
            int cin = p * 4 + c4;
            tile[xx * 72 + cin] = (_Float16)xp[(size_t)cin * 4096 + xx];
        }
        __syncthreads();
        const int oct = t & 7;
        const int xl  = t >> 3;
        _Float16* op = xh + ((((size_t)b * 64 + y) * 64) << 6);
#pragma unroll
        for (int p = 0; p < 2; ++p) {
            int xr = p * 32 + xl;
            half8 v = *(const half8*)&tile[xr * 72 + oct * 8];
            *(half8*)&op[(size_t)xr * 64 + oct * 8] = v;
        }
    } else {
        int e = (bi - 1024) * 256 + t;
        if (e < W2T_HALFS) {
            int kl = e & 31, co = (e >> 5) & 63, i = e >> 11;
            int tap = i >> 1, cin = (i & 1) * 32 + kl;
            w2t[e] = (_Float16)w_dcn[co * 576 + cin * 9 + tap];
        } else {
            int e2 = e - W2T_HALFS;
            int kl = e2 & 31, co = (e2 >> 5) & 31, i = e2 >> 10;
            int tap = i >> 1, cin = (i & 1) * 32 + kl;
            woff2t[e2] = (co < KOFF) ? (_Float16)w_off[co * 576 + cin * 9 + tap]
                                     : (_Float16)0.f;
        }
    }
}

// ---------------------------------------------------------------------------
__launch_bounds__(256, 4)
__global__ void dcn_main(const _Float16* __restrict__ xh,
                         const _Float16* __restrict__ w2t,
                         const _Float16* __restrict__ woff2t,
                         const float* __restrict__ b_off,
                         const float* __restrict__ b_dcn,
                         float* __restrict__ out) {
    const int bid = blockIdx.x;                 // 0..2047
    const int s   = bid >> 3;
    const int b   = ((bid & 7) << 1) | (s >> 7);
    const int ho  = (s >> 1) & 63;
    const int hlf = s & 1;
    const int t    = threadIdx.x;
    const int lane = t & 63;
    const int wid  = __builtin_amdgcn_readfirstlane(t >> 6);
    const int r    = lane & 15;
    const int q    = lane >> 4;
    const int gpx  = t >> 3;                    // 0..31 gather pixel
    const int oct  = t & 7;                     // 8-cin octet
    const int pxg  = hlf * 32;

    __shared__ __align__(16) _Float16 colsT[2][32 * CTS];   // 17408 B
    __shared__ __align__(16) float    offlds[KOFF * 32];    // 2304 B
    __shared__ __align__(16) uint4    grecL[9 * GSTR];      // 4752 B

    const _Float16* xb = xh + ((size_t)b << 18);
    const char* xpb = (const char*)xb;

    // ===== Phase A: offset conv via MFMA, B-frags DIRECT from global ======
    // lane (q,r) of wave (m = wid&1 co-tile, n = wid>>1 px-tile):
    //   B[k = g*32 + q*8 + j][npx = n*16 + r] = xh[y][xc][g*32 + q*8 + j]
    {
        floatx4 am = {0.f, 0.f, 0.f, 0.f};
        const int m = wid & 1, n = wid >> 1;
#pragma unroll
        for (int tap = 0; tap < 9; ++tap) {
            const int dy = tap / 3, dxk = tap - dy * 3;
            const int y  = ho + dy - 1;
            const int xc = pxg + n * 16 + r + dxk - 1;
            const bool ok = ((unsigned)y < 64u) && ((unsigned)xc < 64u);
            const _Float16* xr = &xb[((size_t)y * 64 + xc) << 6];
            half8 b0 = {}, b1 = {};
            if (ok) {
                b0 = *(const half8*)&xr[q * 8];
                b1 = *(const half8*)&xr[32 + q * 8];
            }
            half8 a0 = *(const half8*)&woff2t[(2 * tap) * 1024
                                              + (m * 16 + r) * 32 + q * 8];
            half8 a1 = *(const half8*)&woff2t[(2 * tap + 1) * 1024
                                              + (m * 16 + r) * 32 + q * 8];
            am = __builtin_amdgcn_mfma_f32_16x16x32_f16(a0, b0, am, 0, 0, 0);
            am = __builtin_amdgcn_mfma_f32_16x16x32_f16(a1, b1, am, 0, 0, 0);
        }
#pragma unroll
        for (int reg = 0; reg < 4; ++reg) {
            int co = m * 16 + q * 4 + reg;
            if (co < KOFF)
                offlds[co * 32 + n * 16 + r] = am[reg] + b_off[co];
        }
    }
    __syncthreads();

    // ================= Geometry records (R9-proven encoding) =============
    for (int e = t; e < 9 * 32; e += 256) {
        int tap = e >> 5, px = e & 31;
        float offy = offlds[(2 * tap) * 32 + px];
        float offx = offlds[(2 * tap + 1) * 32 + px];
        float py  = offy + (float)(tap / 3) + (float)(ho - 1);
        float pxf = offx + (float)(tap % 3) + (float)(pxg + px - 1);
        float fy = floorf(py), fx = floorf(pxf);
        int y0 = (int)fy, x0 = (int)fx;
        float wy1 = py - fy, wx1 = pxf - fx;
        float wy0 = 1.f - wy1, wx0 = 1.f - wx1;
        bool y0ok = ((unsigned)y0 < 64u);
        bool x0ok = ((unsigned)x0 < 64u);
        bool y1ok = ((unsigned)(y0 + 1) < 64u);
        bool x1ok = ((unsigned)(x0 + 1) < 64u);
        float w00 = (y0ok && x0ok) ? wy0 * wx0 : 0.f;
        float w01 = (y0ok && x1ok) ? wy0 * wx1 : 0.f;
        float w10 = (y1ok && x0ok) ? wy1 * wx0 : 0.f;
        float w11 = (y1ok && x1ok) ? wy1 * wx1 : 0.f;
        int yc0 = min(max(y0, 0), 63);
        int xc0 = min(max(x0, 0), 63);
        int yc1 = min(max(y0 + 1, 0), 63);
        int xc1 = min(max(x0 + 1, 0), 63);
        union { __half2 h; unsigned u; } c0, c1;
        c0.h = __floats2half2_rn(w00, w01);
        c1.h = __floats2half2_rn(w10, w11);
        uint4 rec;
        rec.x = (unsigned)(yc0 * 64 + xc0)
              | ((unsigned)(xc1 - xc0) << 12)
              | ((unsigned)(yc1 - yc0) << 13);
        rec.y = c0.u;
        rec.z = c1.u;
        rec.w = 0u;
        grecL[tap * GSTR + px] = rec;
    }
    __syncthreads();

    // ================= Phase B: gather + MFMA (tap pairs) ================
    floatx4 acc0 = {0.f, 0.f, 0.f, 0.f};
    floatx4 acc1 = {0.f, 0.f, 0.f, 0.f};

    struct GP { H8 v[8]; unsigned wy0, wz0, wy1, wz1; };

    auto loadPairB = [&](int p) -> GP {
        GP g;
#pragma unroll
        for (int l = 0; l < 2; ++l) {
            int tap = 2 * p + l;
            if (tap < 9) {
                uint4 rec = grecL[tap * GSTR + gpx];
                unsigned a00 = (rec.x & 0xfffu) * 128u + (unsigned)oct * 16u;
                unsigned dx128  = ((rec.x >> 12) & 1u) * 128u;
                unsigned dy8192 = ((rec.x >> 13) & 1u) * 8192u;
                g.v[4 * l + 0].v = *(const half8*)(xpb + a00);
                g.v[4 * l + 1].v = *(const half8*)(xpb + a00 + dx128);
                g.v[4 * l + 2].v = *(const half8*)(xpb + a00 + dy8192);
                g.v[4 * l + 3].v = *(const half8*)(xpb + a00 + dy8192 + dx128);
                if (l == 0) { g.wy0 = rec.y; g.wz0 = rec.z; }
                else        { g.wy1 = rec.y; g.wz1 = rec.z; }
            }
        }
        return g;
    };
    auto storePairB = [&](int p, int buf, GP& g) {
#pragma unroll
        for (int l = 0; l < 2; ++l) {
            int tap = 2 * p + l;
            if (tap < 9) {
                union { unsigned u; __half2 h; } cy, cz;
                cy.u = l ? g.wy1 : g.wy0;
                cz.u = l ? g.wz1 : g.wz0;
                __half2 W00 = __half2half2(__low2half(cy.h));
                __half2 W01 = __half2half2(__high2half(cy.h));
                __half2 W10 = __half2half2(__low2half(cz.h));
                __half2 W11 = __half2half2(__high2half(cz.h));
                H8 res;
#pragma unroll
                for (int c = 0; c < 4; ++c) {
                    __half2 aa = __hmul2(g.v[4 * l + 0].h2[c], W00);
                    aa = __hfma2(g.v[4 * l + 1].h2[c], W01, aa);
                    aa = __hfma2(g.v[4 * l + 2].h2[c], W10, aa);
                    aa = __hfma2(g.v[4 * l + 3].h2[c], W11, aa);
                    res.h2[c] = aa;
                }
                *(half8*)&colsT[buf][gpx * CTS + l * 64 + oct * 8] = res.v;
            }
        }
    };
    auto loadW = [&](int i) -> half8 {
        return *(const half8*)&w2t[(size_t)i * 2048 + (wid * 16 + r) * 32 + q * 8];
    };

    {
        GP g0 = loadPairB(0);
        storePairB(0, 0, g0);
    }
    half8 wf[4];
#pragma unroll
    for (int kg = 0; kg < 4; ++kg) wf[kg] = loadW(kg);
    __syncthreads();

#pragma unroll
    for (int p = 0; p < 5; ++p) {
        GP gn;
        half8 wfn[4];
        if (p < 4) {
            gn = loadPairB(p + 1);
#pragma unroll
            for (int kg = 0; kg < 4; ++kg)
                if (4 * (p + 1) + kg < 18) wfn[kg] = loadW(4 * (p + 1) + kg);
        }
        const int nkg = (p < 4) ? 4 : 2;
#pragma unroll
        for (int kg = 0; kg < 4; ++kg) {
            if (kg < nkg) {
                half8 b0 = *(const half8*)&colsT[p & 1][r * CTS + kg * 32 + q * 8];
                half8 b1 = *(const half8*)&colsT[p & 1][(16 + r) * CTS + kg * 32 + q * 8];
                acc0 = __builtin_amdgcn_mfma_f32_16x16x32_f16(wf[kg], b0, acc0, 0, 0, 0);
                acc1 = __builtin_amdgcn_mfma_f32_16x16x32_f16(wf[kg], b1, acc1, 0, 0, 0);
            }
        }
        if (p < 4) {
            storePairB(p + 1, (p + 1) & 1, gn);   // vmcnt waits AFTER the MFMAs
#pragma unroll
            for (int kg = 0; kg < 4; ++kg) wf[kg] = wfn[kg];
            __syncthreads();
        }
    }

    // ================= epilogue ==========================================
#pragma unroll
    for (int reg = 0; reg < 4; ++reg) {
        int co = wid * 16 + q * 4 + reg;
        float bias = b_dcn[co];
        size_t o = (((size_t)b * 64 + co) * 64 + ho) * 64 + pxg;
        out[o + r]      = acc0[reg] + bias;
        out[o + 16 + r] = acc1[reg] + bias;
    }
}

// ---------------------------------------------------------------------------
// Fallback (R11-proven, x f32 direct) used only if ws too small.
#define FCPAD 40
__launch_bounds__(256, 4)
__global__ void dcn_fb(const float* __restrict__ x,
                       const float* __restrict__ w_dcn,
                       const float* __restrict__ w_off,
                       const float* __restrict__ b_off,
                       const float* __restrict__ b_dcn,
                       float* __restrict__ out) {
    const int bid = blockIdx.x;
    const int s   = bid >> 3;
    const int b   = ((bid & 7) << 1) | (s >> 7);
    const int ho  = (s >> 1) & 63;
    const int hlf = s & 1;
    const int t    = threadIdx.x;
    const int lane = t & 63;
    const int wid  = __builtin_amdgcn_readfirstlane(t >> 6);
    const int r    = lane & 15;
    const int q    = lane >> 4;
    const int px   = t & 31;
    const int kq   = t >> 5;

    __shared__ __align__(16) _Float16 colsT[2][32 * FCPAD];
    __shared__ __align__(16) float    offlds[KOFF * 32];

    const float* xb = x + (size_t)b * 64 * 4096;
    const int pxg = hlf * 32;

    {
        floatx4 am = {0.f, 0.f, 0.f, 0.f};
        const int m = wid & 1, n = wid >> 1;
        auto stageA = [&](int i) {
            const int tap = i >> 1;
            const int dy = tap / 3, dxk = tap - dy * 3;
            const int y  = ho + dy - 1;
            const int xc = pxg + px + dxk - 1;
            const bool ok = ((unsigned)y < 64u) && ((unsigned)xc < 64u);
            const float* xp = xb + ((size_t)((i & 1) * 32 + kq * 4)) * 4096
                                 + y * 64 + xc;
            float va[4];
#pragma unroll
            for (int j = 0; j < 4; ++j) va[j] = ok ? xp[(size_t)j * 4096] : 0.f;
#pragma unroll
            for (int j = 0; j < 4; ++j)
                colsT[i & 1][px * FCPAD + kq * 4 + j] = (_Float16)va[j];
        };
        auto loadA = [&](int i) -> half8 {
            const int tap = i >> 1;
            const int cin0 = (i & 1) * 32 + q * 8;
            const int co = m * 16 + r;
            half8 v;
#pragma unroll
            for (int j = 0; j < 8; ++j)
                v[j] = (co < KOFF) ? (_Float16)w_off[co * 576 + (cin0 + j) * 9 + tap]
                                   : (_Float16)0.f;
            return v;
        };
        stageA(0);
        __syncthreads();
#pragma unroll
        for (int i = 0; i < 18; ++i) {
            if (i < 17) stageA(i + 1);
            half8 a = loadA(i);
            half8 bfr = *(const half8*)&colsT[i & 1][(n * 16 + r) * FCPAD + q * 8];
            am = __builtin_amdgcn_mfma_f32_16x16x32_f16(a, bfr, am, 0, 0, 0);
            __syncthreads();
        }
#pragma unroll
        for (int reg = 0; reg < 4; ++reg) {
            int co = m * 16 + q * 4 + reg;
            if (co < KOFF)
                offlds[co * 32 + (n * 16 + r)] = am[reg] + b_off[co];
        }
    }
    __syncthreads();

    unsigned rmeta[9], rw0[9], rw1[9];
#pragma unroll
    for (int tap = 0; tap < 9; ++tap) {
        float offy = offlds[(2 * tap) * 32 + px];
        float offx = offlds[(2 * tap + 1) * 32 + px];
        float py  = offy + (float)(tap / 3) + (float)(ho - 1);
        float pxf = offx + (float)(tap % 3) + (float)(pxg + px - 1);
        float fy = floorf(py), fx = floorf(pxf);
        int y0 = (int)fy, x0 = (int)fx;
        float wy1 = py - fy, wx1 = pxf - fx;
        float wy0 = 1.f - wy1, wx0 = 1.f - wx1;
        bool y0ok = ((unsigned)y0 < 64u);
        bool x0ok = ((unsigned)x0 < 64u);
        bool y1ok = ((unsigned)(y0 + 1) < 64u);
        bool x1ok = ((unsigned)(x0 + 1) < 64u);
        float w00 = (y0ok && x0ok) ? wy0 * wx0 : 0.f;
        float w01 = (y0ok && x1ok) ? wy0 * wx1 : 0.f;
        float w10 = (y1ok && x0ok) ? wy1 * wx0 : 0.f;
        float w11 = (y1ok && x1ok) ? wy1 * wx1 : 0.f;
        int yc0 = min(max(y0, 0), 63);
        int xc0 = min(max(x0, 0), 63);
        int yc1 = min(max(y0 + 1, 0), 63);
        int xc1 = min(max(x0 + 1, 0), 63);
        union { __half2 h; unsigned u; } c0, c1;
        c0.h = __floats2half2_rn(w00, w01);
        c1.h = __floats2half2_rn(w10, w11);
        rmeta[tap] = (unsigned)(yc0 * 64 + xc0)
                   | ((unsigned)(xc1 - xc0) << 12)
                   | ((unsigned)(yc1 - yc0) << 13);
        rw0[tap] = c0.u;
        rw1[tap] = c1.u;
    }

    floatx4 acc0 = {0.f, 0.f, 0.f, 0.f};
    floatx4 acc1 = {0.f, 0.f, 0.f, 0.f};

    auto gather = [&](int i) {
        const int tap = i >> 1;
        const unsigned m = rmeta[tap];
        const unsigned a00 = (m & 0xfffu) << 2;
        const unsigned a01 = a00 + ((m >> 10) & 4u);
        const unsigned a10 = a00 + ((m >> 5) & 256u);
        const unsigned a11 = a10 + ((m >> 10) & 4u);
        const char* base = (const char*)xb
                         + ((size_t)((i & 1) * 32 + kq * 4)) * 16384;
        float v00[4], v01[4], v10[4], v11[4];
#pragma unroll
        for (int j = 0; j < 4; ++j) {
            const char* xp = base + (size_t)j * 16384;
            v00[j] = *(const float*)(xp + a00);
            v01[j] = *(const float*)(xp + a01);
            v10[j] = *(const float*)(xp + a10);
            v11[j] = *(const float*)(xp + a11);
        }
        union { unsigned u; __half2 h; } c0, c1;
        c0.u = rw0[tap]; c1.u = rw1[tap];
        const float wA = __half2float(c0.h.x), wB = __half2float(c0.h.y);
        const float wC = __half2float(c1.h.x), wD = __half2float(c1.h.y);
#pragma unroll
        for (int j = 0; j < 4; ++j)
            colsT[i & 1][px * FCPAD + kq * 4 + j] =
                (_Float16)(v00[j] * wA + v01[j] * wB + v10[j] * wC + v11[j] * wD);
    };

    auto load_af = [&](int i) -> half8 {
        const int tap = i >> 1;
        const int cin0 = (i & 1) * 32 + q * 8;
        half8 v;
#pragma unroll
        for (int j = 0; j < 8; ++j)
            v[j] = (_Float16)w_dcn[(wid * 16 + r) * 576 + (cin0 + j) * 9 + tap];
        return v;
    };

    gather(0);
    __syncthreads();
#pragma unroll
    for (int i = 0; i < 18; ++i) {
        if (i < 17) gather(i + 1);
        half8 af = load_af(i);
        half8 b0 = *(const half8*)&colsT[i & 1][r * FCPAD + q * 8];
        half8 b1 = *(const half8*)&colsT[i & 1][(16 + r) * FCPAD + q * 8];
        acc0 = __builtin_amdgcn_mfma_f32_16x16x32_f16(af, b0, acc0, 0, 0, 0);
        acc1 = __builtin_amdgcn_mfma_f32_16x16x32_f16(af, b1, acc1, 0, 0, 0);
        if (i < 17) __syncthreads();
    }

#pragma unroll
    for (int reg = 0; reg < 4; ++reg) {
        int co = wid * 16 + q * 4 + reg;
        float bias = b_dcn[co];
        size_t o = (((size_t)b * 64 + co) * 64 + ho) * 64 + pxg;
        out[o + r]      = acc0[reg] + bias;
        out[o + 16 + r] = acc1[reg] + bias;
    }
}

// ---------------------------------------------------------------------------
extern "C" void kernel_launch(void* const* d_in, const int* in_sizes, int n_in,
                              void* d_out, int out_size, void* d_ws, size_t ws_size,
                              hipStream_t stream) {
    const float* x     = (const float*)d_in[0];
    const float* w_off = (const float*)d_in[1];
    const float* b_off = (const float*)d_in[2];
    const float* w_dcn = (const float*)d_in[3];
    const float* b_dcn = (const float*)d_in[4];
    float* out = (float*)d_out;

    char* ws = (char*)d_ws;
    _Float16* w2t    = (_Float16*)ws;
    _Float16* woff2t = (_Float16*)(ws + WOFF2T_OFF);
    _Float16* xh     = (_Float16*)(ws + X_OFF);

    if (ws_size >= (size_t)WS_NEED) {
        prep<<<1240, 256, 0, stream>>>(x, w_dcn, w_off, w2t, woff2t, xh);
        dcn_main<<<2048, 256, 0, stream>>>(xh, w2t, woff2t, b_off, b_dcn, out);
    } else {
        dcn_fb<<<2048, 256, 0, stream>>>(x, w_dcn, w_off, b_off, b_dcn, out);
    }
}

// Round 16
// 108.168 us; speedup vs baseline: 1.1129x; 1.1129x over previous
//
#include <hip/hip_runtime.h>
#include <hip/hip_fp16.h>

// DeformConv2d: B=16, Cin=64, Cout=64, H=W=64, K=3, stride=1, pad=1, dil=1
// Round 16: exact revert to R14 (best passing, 108.6us). R15's phase-A
// direct-global B-frags regressed (49us vs ~43: 2x scattered VMEM, lost
// LDS sharing between co-tile waves). R14 config: NHWC-f16 x copy (ws),
// tap-major f16 weights, MFMA phase A with LDS staging, tap-PAIR phase B
// (K=128 per barrier, batched gather loads, vmcnt drains behind MFMAs).

#define KOFF 18
#define CTS  136           // colsT stride in halfs (2*64 cin + 8 pad)
#define GSTR 33            // LDS geometry record stride (uint4)

#define W2T_HALFS    (18 * 64 * 32)     // [i][64co][32kl], k' = tap*64+cin
#define WOFF2T_HALFS (18 * 32 * 32)     // [i][32co][32kl]
#define W2T_BYTES    (W2T_HALFS * 2)    // 73728
#define WOFF2T_OFF   W2T_BYTES
#define X_OFF        (W2T_BYTES + WOFF2T_HALFS * 2)   // 110592 (16B aligned)
#define XH_BYTES     (16 * 64 * 64 * 64 * 2)          // 8388608
#define WS_NEED      (X_OFF + XH_BYTES)               // 8499200

typedef _Float16 half8 __attribute__((ext_vector_type(8)));
typedef float floatx4 __attribute__((ext_vector_type(4)));

union H8 { half8 v; __half2 h2[4]; uint4 u; };

// ---------------------------------------------------------------------------
// prep: blocks [0,1024): LDS-tiled transpose of one (b,y) plane (coalesced
// both sides). blocks [1024,1240): weight repack (tap-major f16).
__global__ void prep(const float* __restrict__ x,
                     const float* __restrict__ w_dcn,
                     const float* __restrict__ w_off,
                     _Float16* __restrict__ w2t,
                     _Float16* __restrict__ woff2t,
                     _Float16* __restrict__ xh) {
    const int bi = blockIdx.x;
    const int t  = threadIdx.x;
    if (bi < 1024) {
        const int b = bi >> 6, y = bi & 63;
        __shared__ __align__(16) _Float16 tile[64 * 72];
        const int xx = t & 63;
        const int c4 = t >> 6;
        const float* xp = x + (((size_t)b * 64) * 64 + y) * 64;
#pragma unroll
        for (int p = 0; p < 16; ++p) {
            int cin = p * 4 + c4;
            tile[xx * 72 + cin] = (_Float16)xp[(size_t)cin * 4096 + xx];
        }
        __syncthreads();
        const int oct = t & 7;
        const int xl  = t >> 3;
        _Float16* op = xh + ((((size_t)b * 64 + y) * 64) << 6);
#pragma unroll
        for (int p = 0; p < 2; ++p) {
            int xr = p * 32 + xl;
            half8 v = *(const half8*)&tile[xr * 72 + oct * 8];
            *(half8*)&op[(size_t)xr * 64 + oct * 8] = v;
        }
    } else {
        int e = (bi - 1024) * 256 + t;
        if (e < W2T_HALFS) {
            int kl = e & 31, co = (e >> 5) & 63, i = e >> 11;
            int tap = i >> 1, cin = (i & 1) * 32 + kl;
            w2t[e] = (_Float16)w_dcn[co * 576 + cin * 9 + tap];
        } else {
            int e2 = e - W2T_HALFS;
            int kl = e2 & 31, co = (e2 >> 5) & 31, i = e2 >> 10;
            int tap = i >> 1, cin = (i & 1) * 32 + kl;
            woff2t[e2] = (co < KOFF) ? (_Float16)w_off[co * 576 + cin * 9 + tap]
                                     : (_Float16)0.f;
        }
    }
}

// ---------------------------------------------------------------------------
__launch_bounds__(256, 4)
__global__ void dcn_main(const _Float16* __restrict__ xh,
                         const _Float16* __restrict__ w2t,
                         const _Float16* __restrict__ woff2t,
                         const float* __restrict__ b_off,
                         const float* __restrict__ b_dcn,
                         float* __restrict__ out) {
    const int bid = blockIdx.x;                 // 0..2047
    const int s   = bid >> 3;
    const int b   = ((bid & 7) << 1) | (s >> 7);
    const int ho  = (s >> 1) & 63;
    const int hlf = s & 1;
    const int t    = threadIdx.x;
    const int lane = t & 63;
    const int wid  = __builtin_amdgcn_readfirstlane(t >> 6);
    const int r    = lane & 15;
    const int q    = lane >> 4;
    const int gpx  = t >> 3;                    // 0..31 gather/stage pixel
    const int oct  = t & 7;                     // 8-cin octet
    const int pxg  = hlf * 32;

    __shared__ __align__(16) _Float16 colsT[2][32 * CTS];   // 17408 B
    __shared__ __align__(16) float    offlds[KOFF * 32];    // 2304 B
    __shared__ __align__(16) uint4    grecL[9 * GSTR];      // 4752 B

    const _Float16* xb = xh + ((size_t)b << 18);
    const char* xpb = (const char*)xb;

    // ================= Phase A: offset conv via MFMA (tap pairs) =========
    {
        floatx4 am = {0.f, 0.f, 0.f, 0.f};
        const int m = wid & 1, n = wid >> 1;

        auto loadS = [&](int tap) -> half8 {
            const int dy = tap / 3, dxk = tap - dy * 3;
            const int y  = ho + dy - 1;
            const int xc = pxg + gpx + dxk - 1;
            half8 v = {};
            if (((unsigned)y < 64u) && ((unsigned)xc < 64u))
                v = *(const half8*)&xb[(((size_t)y * 64 + xc) << 6) + oct * 8];
            return v;
        };
        auto loadWA = [&](int i) -> half8 {
            return *(const half8*)&woff2t[i * 1024 + (m * 16 + r) * 32 + q * 8];
        };

        {
            half8 s0 = loadS(0), s1 = loadS(1);
            *(half8*)&colsT[0][gpx * CTS + oct * 8]      = s0;
            *(half8*)&colsT[0][gpx * CTS + 64 + oct * 8] = s1;
        }
        __syncthreads();
#pragma unroll
        for (int p = 0; p < 5; ++p) {
            half8 sn0, sn1;
            if (p < 4) {
                sn0 = loadS(2 * p + 2);
                if (p < 3) sn1 = loadS(2 * p + 3);
            }
            const int nkg = (p < 4) ? 4 : 2;
#pragma unroll
            for (int kg = 0; kg < 4; ++kg) {
                if (kg < nkg) {
                    half8 a  = loadWA(4 * p + kg);
                    half8 bf = *(const half8*)&colsT[p & 1][(n * 16 + r) * CTS
                                                            + kg * 32 + q * 8];
                    am = __builtin_amdgcn_mfma_f32_16x16x32_f16(a, bf, am, 0, 0, 0);
                }
            }
            if (p < 4) {
                *(half8*)&colsT[(p + 1) & 1][gpx * CTS + oct * 8] = sn0;
                if (p < 3)
                    *(half8*)&colsT[(p + 1) & 1][gpx * CTS + 64 + oct * 8] = sn1;
                __syncthreads();
            }
        }
#pragma unroll
        for (int reg = 0; reg < 4; ++reg) {
            int co = m * 16 + q * 4 + reg;
            if (co < KOFF)
                offlds[co * 32 + n * 16 + r] = am[reg] + b_off[co];
        }
    }
    __syncthreads();

    // ================= Geometry records (R9-proven encoding) =============
    for (int e = t; e < 9 * 32; e += 256) {
        int tap = e >> 5, px = e & 31;
        float offy = offlds[(2 * tap) * 32 + px];
        float offx = offlds[(2 * tap + 1) * 32 + px];
        float py  = offy + (float)(tap / 3) + (float)(ho - 1);
        float pxf = offx + (float)(tap % 3) + (float)(pxg + px - 1);
        float fy = floorf(py), fx = floorf(pxf);
        int y0 = (int)fy, x0 = (int)fx;
        float wy1 = py - fy, wx1 = pxf - fx;
        float wy0 = 1.f - wy1, wx0 = 1.f - wx1;
        bool y0ok = ((unsigned)y0 < 64u);
        bool x0ok = ((unsigned)x0 < 64u);
        bool y1ok = ((unsigned)(y0 + 1) < 64u);
        bool x1ok = ((unsigned)(x0 + 1) < 64u);
        float w00 = (y0ok && x0ok) ? wy0 * wx0 : 0.f;
        float w01 = (y0ok && x1ok) ? wy0 * wx1 : 0.f;
        float w10 = (y1ok && x0ok) ? wy1 * wx0 : 0.f;
        float w11 = (y1ok && x1ok) ? wy1 * wx1 : 0.f;
        int yc0 = min(max(y0, 0), 63);
        int xc0 = min(max(x0, 0), 63);
        int yc1 = min(max(y0 + 1, 0), 63);
        int xc1 = min(max(x0 + 1, 0), 63);
        union { __half2 h; unsigned u; } c0, c1;
        c0.h = __floats2half2_rn(w00, w01);
        c1.h = __floats2half2_rn(w10, w11);
        uint4 rec;
        rec.x = (unsigned)(yc0 * 64 + xc0)
              | ((unsigned)(xc1 - xc0) << 12)
              | ((unsigned)(yc1 - yc0) << 13);
        rec.y = c0.u;
        rec.z = c1.u;
        rec.w = 0u;
        grecL[tap * GSTR + px] = rec;
    }
    __syncthreads();

    // ================= Phase B: gather + MFMA (tap pairs) ================
    floatx4 acc0 = {0.f, 0.f, 0.f, 0.f};
    floatx4 acc1 = {0.f, 0.f, 0.f, 0.f};

    struct GP { H8 v[8]; unsigned wy0, wz0, wy1, wz1; };

    auto loadPairB = [&](int p) -> GP {
        GP g;
#pragma unroll
        for (int l = 0; l < 2; ++l) {
            int tap = 2 * p + l;
            if (tap < 9) {
                uint4 rec = grecL[tap * GSTR + gpx];
                unsigned a00 = (rec.x & 0xfffu) * 128u + (unsigned)oct * 16u;
                unsigned dx128  = ((rec.x >> 12) & 1u) * 128u;
                unsigned dy8192 = ((rec.x >> 13) & 1u) * 8192u;
                g.v[4 * l + 0].v = *(const half8*)(xpb + a00);
                g.v[4 * l + 1].v = *(const half8*)(xpb + a00 + dx128);
                g.v[4 * l + 2].v = *(const half8*)(xpb + a00 + dy8192);
                g.v[4 * l + 3].v = *(const half8*)(xpb + a00 + dy8192 + dx128);
                if (l == 0) { g.wy0 = rec.y; g.wz0 = rec.z; }
                else        { g.wy1 = rec.y; g.wz1 = rec.z; }
            }
        }
        return g;
    };
    auto storePairB = [&](int p, int buf, GP& g) {
#pragma unroll
        for (int l = 0; l < 2; ++l) {
            int tap = 2 * p + l;
            if (tap < 9) {
                union { unsigned u; __half2 h; } cy, cz;
                cy.u = l ? g.wy1 : g.wy0;
                cz.u = l ? g.wz1 : g.wz0;
                __half2 W00 = __half2half2(__low2half(cy.h));
                __half2 W01 = __half2half2(__high2half(cy.h));
                __half2 W10 = __half2half2(__low2half(cz.h));
                __half2 W11 = __half2half2(__high2half(cz.h));
                H8 res;
#pragma unroll
                for (int c = 0; c < 4; ++c) {
                    __half2 aa = __hmul2(g.v[4 * l + 0].h2[c], W00);
                    aa = __hfma2(g.v[4 * l + 1].h2[c], W01, aa);
                    aa = __hfma2(g.v[4 * l + 2].h2[c], W10, aa);
                    aa = __hfma2(g.v[4 * l + 3].h2[c], W11, aa);
                    res.h2[c] = aa;
                }
                *(half8*)&colsT[buf][gpx * CTS + l * 64 + oct * 8] = res.v;
            }
        }
    };
    auto loadW = [&](int i) -> half8 {
        return *(const half8*)&w2t[(size_t)i * 2048 + (wid * 16 + r) * 32 + q * 8];
    };

    {
        GP g0 = loadPairB(0);
        storePairB(0, 0, g0);
    }
    half8 wf[4];
#pragma unroll
    for (int kg = 0; kg < 4; ++kg) wf[kg] = loadW(kg);
    __syncthreads();

#pragma unroll
    for (int p = 0; p < 5; ++p) {
        GP gn;
        half8 wfn[4];
        if (p < 4) {
            gn = loadPairB(p + 1);
#pragma unroll
            for (int kg = 0; kg < 4; ++kg)
                if (4 * (p + 1) + kg < 18) wfn[kg] = loadW(4 * (p + 1) + kg);
        }
        const int nkg = (p < 4) ? 4 : 2;
#pragma unroll
        for (int kg = 0; kg < 4; ++kg) {
            if (kg < nkg) {
                half8 b0 = *(const half8*)&colsT[p & 1][r * CTS + kg * 32 + q * 8];
                half8 b1 = *(const half8*)&colsT[p & 1][(16 + r) * CTS + kg * 32 + q * 8];
                acc0 = __builtin_amdgcn_mfma_f32_16x16x32_f16(wf[kg], b0, acc0, 0, 0, 0);
                acc1 = __builtin_amdgcn_mfma_f32_16x16x32_f16(wf[kg], b1, acc1, 0, 0, 0);
            }
        }
        if (p < 4) {
            storePairB(p + 1, (p + 1) & 1, gn);   // vmcnt waits AFTER the MFMAs
#pragma unroll
            for (int kg = 0; kg < 4; ++kg) wf[kg] = wfn[kg];
            __syncthreads();
        }
    }

    // ================= epilogue ==========================================
#pragma unroll
    for (int reg = 0; reg < 4; ++reg) {
        int co = wid * 16 + q * 4 + reg;
        float bias = b_dcn[co];
        size_t o = (((size_t)b * 64 + co) * 64 + ho) * 64 + pxg;
        out[o + r]      = acc0[reg] + bias;
        out[o + 16 + r] = acc1[reg] + bias;
    }
}

// ---------------------------------------------------------------------------
// Fallback (R11-proven, x f32 direct) used only if ws too small.
#define FCPAD 40
__launch_bounds__(256, 4)
__global__ void dcn_fb(const float* __restrict__ x,
                       const float* __restrict__ w_dcn,
                       const float* __restrict__ w_off,
                       const float* __restrict__ b_off,
                       const float* __restrict__ b_dcn,
                       float* __restrict__ out) {
    const int bid = blockIdx.x;
    const int s   = bid >> 3;
    const int b   = ((bid & 7) << 1) | (s >> 7);
    const int ho  = (s >> 1) & 63;
    const int hlf = s & 1;
    const int t    = threadIdx.x;
    const int lane = t & 63;
    const int wid  = __builtin_amdgcn_readfirstlane(t >> 6);
    const int r    = lane & 15;
    const int q    = lane >> 4;
    const int px   = t & 31;
    const int kq   = t >> 5;

    __shared__ __align__(16) _Float16 colsT[2][32 * FCPAD];
    __shared__ __align__(16) float    offlds[KOFF * 32];

    const float* xb = x + (size_t)b * 64 * 4096;
    const int pxg = hlf * 32;

    {
        floatx4 am = {0.f, 0.f, 0.f, 0.f};
        const int m = wid & 1, n = wid >> 1;
        auto stageA = [&](int i) {
            const int tap = i >> 1;
            const int dy = tap / 3, dxk = tap - dy * 3;
            const int y  = ho + dy - 1;
            const int xc = pxg + px + dxk - 1;
            const bool ok = ((unsigned)y < 64u) && ((unsigned)xc < 64u);
            const float* xp = xb + ((size_t)((i & 1) * 32 + kq * 4)) * 4096
                                 + y * 64 + xc;
            float va[4];
#pragma unroll
            for (int j = 0; j < 4; ++j) va[j] = ok ? xp[(size_t)j * 4096] : 0.f;
#pragma unroll
            for (int j = 0; j < 4; ++j)
                colsT[i & 1][px * FCPAD + kq * 4 + j] = (_Float16)va[j];
        };
        auto loadA = [&](int i) -> half8 {
            const int tap = i >> 1;
            const int cin0 = (i & 1) * 32 + q * 8;
            const int co = m * 16 + r;
            half8 v;
#pragma unroll
            for (int j = 0; j < 8; ++j)
                v[j] = (co < KOFF) ? (_Float16)w_off[co * 576 + (cin0 + j) * 9 + tap]
                                   : (_Float16)0.f;
            return v;
        };
        stageA(0);
        __syncthreads();
#pragma unroll
        for (int i = 0; i < 18; ++i) {
            if (i < 17) stageA(i + 1);
            half8 a = loadA(i);
            half8 bfr = *(const half8*)&colsT[i & 1][(n * 16 + r) * FCPAD + q * 8];
            am = __builtin_amdgcn_mfma_f32_16x16x32_f16(a, bfr, am, 0, 0, 0);
            __syncthreads();
        }
#pragma unroll
        for (int reg = 0; reg < 4; ++reg) {
            int co = m * 16 + q * 4 + reg;
            if (co < KOFF)
                offlds[co * 32 + (n * 16 + r)] = am[reg] + b_off[co];
        }
    }
    __syncthreads();

    unsigned rmeta[9], rw0[9], rw1[9];
#pragma unroll
    for (int tap = 0; tap < 9; ++tap) {
        float offy = offlds[(2 * tap) * 32 + px];
        float offx = offlds[(2 * tap + 1) * 32 + px];
        float py  = offy + (float)(tap / 3) + (float)(ho - 1);
        float pxf = offx + (float)(tap % 3) + (float)(pxg + px - 1);
        float fy = floorf(py), fx = floorf(pxf);
        int y0 = (int)fy, x0 = (int)fx;
        float wy1 = py - fy, wx1 = pxf - fx;
        float wy0 = 1.f - wy1, wx0 = 1.f - wx1;
        bool y0ok = ((unsigned)y0 < 64u);
        bool x0ok = ((unsigned)x0 < 64u);
        bool y1ok = ((unsigned)(y0 + 1) < 64u);
        bool x1ok = ((unsigned)(x0 + 1) < 64u);
        float w00 = (y0ok && x0ok) ? wy0 * wx0 : 0.f;
        float w01 = (y0ok && x1ok) ? wy0 * wx1 : 0.f;
        float w10 = (y1ok && x0ok) ? wy1 * wx0 : 0.f;
        float w11 = (y1ok && x1ok) ? wy1 * wx1 : 0.f;
        int yc0 = min(max(y0, 0), 63);
        int xc0 = min(max(x0, 0), 63);
        int yc1 = min(max(y0 + 1, 0), 63);
        int xc1 = min(max(x0 + 1, 0), 63);
        union { __half2 h; unsigned u; } c0, c1;
        c0.h = __floats2half2_rn(w00, w01);
        c1.h = __floats2half2_rn(w10, w11);
        rmeta[tap] = (unsigned)(yc0 * 64 + xc0)
                   | ((unsigned)(xc1 - xc0) << 12)
                   | ((unsigned)(yc1 - yc0) << 13);
        rw0[tap] = c0.u;
        rw1[tap] = c1.u;
    }

    floatx4 acc0 = {0.f, 0.f, 0.f, 0.f};
    floatx4 acc1 = {0.f, 0.f, 0.f, 0.f};

    auto gather = [&](int i) {
        const int tap = i >> 1;
        const unsigned m = rmeta[tap];
        const unsigned a00 = (m & 0xfffu) << 2;
        const unsigned a01 = a00 + ((m >> 10) & 4u);
        const unsigned a10 = a00 + ((m >> 5) & 256u);
        const unsigned a11 = a10 + ((m >> 10) & 4u);
        const char* base = (const char*)xb
                         + ((size_t)((i & 1) * 32 + kq * 4)) * 16384;
        float v00[4], v01[4], v10[4], v11[4];
#pragma unroll
        for (int j = 0; j < 4; ++j) {
            const char* xp = base + (size_t)j * 16384;
            v00[j] = *(const float*)(xp + a00);
            v01[j] = *(const float*)(xp + a01);
            v10[j] = *(const float*)(xp + a10);
            v11[j] = *(const float*)(xp + a11);
        }
        union { unsigned u; __half2 h; } c0, c1;
        c0.u = rw0[tap]; c1.u = rw1[tap];
        const float wA = __half2float(c0.h.x), wB = __half2float(c0.h.y);
        const float wC = __half2float(c1.h.x), wD = __half2float(c1.h.y);
#pragma unroll
        for (int j = 0; j < 4; ++j)
            colsT[i & 1][px * FCPAD + kq * 4 + j] =
                (_Float16)(v00[j] * wA + v01[j] * wB + v10[j] * wC + v11[j] * wD);
    };

    auto load_af = [&](int i) -> half8 {
        const int tap = i >> 1;
        const int cin0 = (i & 1) * 32 + q * 8;
        half8 v;
#pragma unroll
        for (int j = 0; j < 8; ++j)
            v[j] = (_Float16)w_dcn[(wid * 16 + r) * 576 + (cin0 + j) * 9 + tap];
        return v;
    };

    gather(0);
    __syncthreads();
#pragma unroll
    for (int i = 0; i < 18; ++i) {
        if (i < 17) gather(i + 1);
        half8 af = load_af(i);
        half8 b0 = *(const half8*)&colsT[i & 1][r * FCPAD + q * 8];
        half8 b1 = *(const half8*)&colsT[i & 1][(16 + r) * FCPAD + q * 8];
        acc0 = __builtin_amdgcn_mfma_f32_16x16x32_f16(af, b0, acc0, 0, 0, 0);
        acc1 = __builtin_amdgcn_mfma_f32_16x16x32_f16(af, b1, acc1, 0, 0, 0);
        if (i < 17) __syncthreads();
    }

#pragma unroll
    for (int reg = 0; reg < 4; ++reg) {
        int co = wid * 16 + q * 4 + reg;
        float bias = b_dcn[co];
        size_t o = (((size_t)b * 64 + co) * 64 + ho) * 64 + pxg;
        out[o + r]      = acc0[reg] + bias;
        out[o + 16 + r] = acc1[reg] + bias;
    }
}

// ---------------------------------------------------------------------------
extern "C" void kernel_launch(void* const* d_in, const int* in_sizes, int n_in,
                              void* d_out, int out_size, void* d_ws, size_t ws_size,
                              hipStream_t stream) {
    const float* x     = (const float*)d_in[0];
    const float* w_off = (const float*)d_in[1];
    const float* b_off = (const float*)d_in[2];
    const float* w_dcn = (const float*)d_in[3];
    const float* b_dcn = (const float*)d_in[4];
    float* out = (float*)d_out;

    char* ws = (char*)d_ws;
    _Float16* w2t    = (_Float16*)ws;
    _Float16* woff2t = (_Float16*)(ws + WOFF2T_OFF);
    _Float16* xh     = (_Float16*)(ws + X_OFF);

    if (ws_size >= (size_t)WS_NEED) {
        prep<<<1240, 256, 0, stream>>>(x, w_dcn, w_off, w2t, woff2t, xh);
        dcn_main<<<2048, 256, 0, stream>>>(xh, w2t, woff2t, b_off, b_dcn, out);
    } else {
        dcn_fb<<<2048, 256, 0, stream>>>(x, w_dcn, w_off, b_off, b_dcn, out);
    }
}